// Round 7
// baseline (209.186 us; speedup 1.0000x reference)
//
#include <hip/hip_runtime.h>

// PSAMask collect: out[n, i*65+j, h, w] = x[n, (i-h+64)*129 + (j-w+64), h, w]
// R7: DIAGONAL pairing. Cells (i,h) and (i+1,h+1) share Mh = i-h+64, so their
// row-u read segments are 260B apart (same DRAM page) -> halves read-side
// page-opens vs R2/R5 (whose paired cells were 2.18MB apart). Same envelope
// as R5: 69KB LDS, 1024 thr, 2 blocks/CU = 32 waves/CU, global_load_lds.
// LDS layout [u][134]: t = 65*hh + min(j,w) (exact identity for the skew).

constexpr int H = 65, W = 65, MH = 129, MW = 129, HALF = 64;
constexpr int HW = H * W;          // 4225
constexpr int P = 134;             // row pitch: store-read deltas -133/-134 -> free / 4-way
constexpr int NPB = 33 * 65;       // 2145 blocks per n (32 pair-rows + 1 single-row)
constexpr int NWG = 4 * NPB;       // 8580

__device__ __forceinline__ void ldsld(const float* g, float* l) {
    __builtin_amdgcn_global_load_lds(
        (const __attribute__((address_space(1))) unsigned int*)g,
        (__attribute__((address_space(3))) unsigned int*)l, 4, 0, 0);
}

__global__ __launch_bounds__(1024, 8)
void psamask_collect(const float* __restrict__ x, float* __restrict__ out) {
    extern __shared__ float lds[];   // 129*134*4 = 69,144 B

    // Bijective XCD-aware swizzle (8580 % 8 == 4 -> m204 formula)
    constexpr int NX = 8, q = NWG / NX, r = NWG % NX;   // 1072, 4
    int b = blockIdx.x;
    int xcd = b % NX, idx = b / NX;
    int logical = (xcd < r ? xcd * (q + 1) : r * (q + 1) + (xcd - r) * q) + idx;

    int n   = logical / NPB;
    int rem = logical - n * NPB;
    int hp  = rem / 65;                // 0..32
    int i0  = rem - hp * 65;           // 0..64  (innermost: write-neighbor blocks adjacent)

    int iA, hA, iB, hB, nh;
    if (hp < 32) {
        nh = 2;
        if (i0 < 64) { iA = i0; hA = 2 * hp; iB = i0 + 1; hB = 2 * hp + 1; }  // diagonal: same Mh
        else         { iA = 64; hA = 2 * hp; iB = 0;      hB = 2 * hp + 1; }  // leftover (no locality)
    } else {
        nh = 1; iA = i0; hA = 64; iB = 0; hB = 0;                              // h=64 singles
    }

    const float* srcA = x + ((size_t)n * (MH * MW) + (size_t)(iA - hA + HALF) * MW) * HW + hA * W;
    const float* srcB = x + ((size_t)n * (MH * MW) + (size_t)(iB - hB + HALF) * MW) * HW + hB * W;

    int wv   = threadIdx.x >> 6;       // 0..15
    int lane = threadIdx.x & 63;

    // Stage: row u, cell hh -> lds[u*P + 65*hh + (w - w0)], w in [w0, w1).
    // Diagonal pair: the two global segments per u are 260B apart -> same page.
    for (int r2 = 0; r2 < 9; ++r2) {
        int u = wv + 16 * r2;
        if (u < MH) {
            int w0 = HALF - u; if (w0 < 0) w0 = 0;
            int w1 = MH - u;   if (w1 > W) w1 = W;
            int len = w1 - w0;                       // 1..65
            float* row = &lds[u * P];
            if (lane < len) ldsld(srcA + (size_t)u * HW + w0 + lane, row);
            if (nh == 2 && lane < len) ldsld(srcB + (size_t)u * HW + w0 + lane, row + 65);
            if (len == 65 && lane == 0) {            // u==64: 65th element
                ldsld(srcA + (size_t)u * HW + w0 + 64, row + 64);
                if (nh == 2) ldsld(srcB + (size_t)u * HW + w0 + 64, row + 65 + 64);
            }
        }
    }
    __syncthreads();   // drains vmcnt(0): both trapezoids resident

    // Store: element (hh, j, w) <- lds[(j-w+64)*P + 65*hh + min(j,w)]
    float* dstA = out + ((size_t)n * HW + (size_t)iA * W) * HW + hA * W;
    float* dstB = out + ((size_t)n * HW + (size_t)iB * W) * HW + hB * W;
    int total = nh * HW;               // 8450 or 4225
    for (int f = (int)threadIdx.x; f < total; f += 1024) {
        int hh = f >= HW ? 1 : 0;
        int g  = f - hh * HW;
        int j  = g / W;
        int w  = g - j * W;
        int t  = j < w ? j : w;
        float v = lds[(j - w + HALF) * P + 65 * hh + t];
        float* d = hh ? dstB : dstA;
        d[(size_t)j * HW + w] = v;
    }
}

extern "C" void kernel_launch(void* const* d_in, const int* in_sizes, int n_in,
                              void* d_out, int out_size, void* d_ws, size_t ws_size,
                              hipStream_t stream) {
    const float* x = (const float*)d_in[0];
    float* out = (float*)d_out;
    (void)in_sizes; (void)n_in; (void)out_size; (void)d_ws; (void)ws_size;
    psamask_collect<<<dim3(NWG), dim3(1024), MH * P * sizeof(float), stream>>>(x, out);
}